// Round 9
// baseline (3104.766 us; speedup 1.0000x reference)
//
#include <hip/hip_runtime.h>
#include <hip/hip_bf16.h>
#include <math.h>

// EMD loss via exact Hungarian (Jonker-Volgenant shortest augmenting path).
// B=32, N=256, D=3. ONE WAVE per batch, 4 columns per lane.
// Round-8/9: LAPJV augmenting row reduction (ARR) between the greedy warm
// start and the exact augmentation loop.
// ARR invariant proof sketch (per step, row i, best col j1, min1/min2):
//   v[j1] -= (min2-min1); u[i] = min2  =>  rc(i,j1)=0 (tight), rc(i,j)>=0;
//   displaced row i1's old edge gains +(min2-min1)>=0 (feasible, now free);
//   all other rows/cols untouched. So dual feasibility + tightness of
//   matched edges hold entering the exact phase => exact optimum unchanged.
// Bounded budget (1024 iters) guarantees termination; leftover free rows are
// handled exactly by the augmentation loop.

#define NPTS   256
#define NBATCH 32
#define FINF   (__builtin_inff())

// one DPP fmin step on f32; masked-out lanes combine with +INF (identity)
template<int CTRL, int ROWM>
__device__ __forceinline__ float dpp_fmin_step(float bv) {
    const int s = __float_as_int(bv);
    const int f = __float_as_int(FINF);
    const int w = __builtin_amdgcn_update_dpp(f, s, CTRL, ROWM, 0xF, false);
    return fminf(bv, __int_as_float(w));
}

// one DPP combine step for (min1, argmin1, min2); identities are +INF
template<int CTRL, int ROWM>
__device__ __forceinline__ void dpp_min12_step(float& m1, int& c1, float& m2) {
    const int fi = __float_as_int(FINF);
    const float n1 = __int_as_float(__builtin_amdgcn_update_dpp(fi, __float_as_int(m1), CTRL, ROWM, 0xF, false));
    const float n2 = __int_as_float(__builtin_amdgcn_update_dpp(fi, __float_as_int(m2), CTRL, ROWM, 0xF, false));
    const int   d1 = __builtin_amdgcn_update_dpp(0,  c1, CTRL, ROWM, 0xF, false);
    const bool  sw = n1 < m1;
    const float lose = sw ? m1 : n1;             // max(m1, n1)
    m1 = sw ? n1 : m1;
    c1 = sw ? d1 : c1;
    m2 = fminf(fminf(m2, n2), lose);             // union second-min
}

__device__ __forceinline__ float readlane_f32(float x, int l) {
    return __uint_as_float((unsigned)__builtin_amdgcn_readlane((int)__float_as_uint(x), l));
}

__global__ __launch_bounds__(64) void emd_hungarian_wave(
    const float* __restrict__ p1,
    const float* __restrict__ p2,
    double* __restrict__ batch_mean)
{
    const int b    = blockIdx.x;
    const int lane = threadIdx.x;

    __shared__ float4 s_p1[NPTS];       // p1 points (immutable after setup)
    __shared__ float4 s_q [NPTS];       // p2 points (immutable after setup)
    __shared__ float  s_u [NPTS + 1];   // row potentials (f32)
    __shared__ int    s_p [NPTS + 1];   // p[j] = row matched to column j
    __shared__ int    s_way[NPTS + 1];  // back pointers

    const float* p1b = p1 + (size_t)b * NPTS * 3;
    const float* p2b = p2 + (size_t)b * NPTS * 3;

    float qx[4], qy[4], qz[4];
    float4 r0, r1, r2, r3;              // own 4 p1 rows, kept in registers
    #pragma unroll
    for (int k = 0; k < 4; ++k) {
        const int idx = lane + 64 * k;
        const float4 pt = make_float4(p1b[idx*3+0], p1b[idx*3+1], p1b[idx*3+2], 0.0f);
        s_p1[idx] = pt;
        if (k == 0) r0 = pt; else if (k == 1) r1 = pt; else if (k == 2) r2 = pt; else r3 = pt;
        const float a = p2b[idx*3+0], c = p2b[idx*3+1], d = p2b[idx*3+2];
        s_q[idx] = make_float4(a, c, d, 0.0f);
        qx[k] = a; qy[k] = c; qz[k] = d;
        s_p[idx + 1] = 0;
    }
    if (lane == 0) { s_u[0] = 0.0f; s_p[0] = 0; }
    __syncthreads();

    // ---- Phase A: row reduction u[r] = min_j c(r,j) (lane owns 4 rows) ----
    {
        float m0 = FINF, m1 = FINF, m2 = FINF, m3 = FINF;   // min squared dist
        for (int j = 0; j < NPTS; ++j) {
            const float4 q = s_q[j];
            #define D2(R) ((R.x-q.x)*(R.x-q.x) + (R.y-q.y)*(R.y-q.y) + (R.z-q.z)*(R.z-q.z))
            m0 = fminf(m0, D2(r0)); m1 = fminf(m1, D2(r1));
            m2 = fminf(m2, D2(r2)); m3 = fminf(m3, D2(r3));
            #undef D2
        }
        // sqrt is monotone: min_j sqrtf(d2) == sqrtf(min_j d2) exactly
        s_u[lane +   1] = sqrtf(m0);
        s_u[lane +  65] = sqrtf(m1);
        s_u[lane + 129] = sqrtf(m2);
        s_u[lane + 193] = sqrtf(m3);
    }
    __syncthreads();

    // ---- Phase B: column reduction v[j] = min_i (c(i,j) - u[i]) ----
    float v0_ = FINF, v1_ = FINF, v2_ = FINF, v3_ = FINF;
    for (int i2 = 0; i2 < NPTS; ++i2) {
        const float4 rr = s_p1[i2];
        const float  ui = s_u[i2 + 1];
        #define CAND(K, VK)                                                    \
            { const float dx = rr.x - qx[K], dy = rr.y - qy[K], dz = rr.z - qz[K]; \
              const float cd = sqrtf(dx*dx + dy*dy + dz*dz) - ui;              \
              VK = fminf(VK, cd); }
        CAND(0, v0_) CAND(1, v1_) CAND(2, v2_) CAND(3, v3_)
        #undef CAND
    }

    // ---- Phase C: greedy matching on exact zeros of reduced cost ----
    unsigned long long um0 = ~0ull, um1 = ~0ull, um2 = ~0ull, um3 = ~0ull; // unmatched cols
    unsigned long long rm0 = 0, rm1 = 0, rm2 = 0, rm3 = 0;                 // matched rows
    int y0 = 0, y1 = 0, y2 = 0, y3 = 0;      // col->row map for own 4 cols
    for (int i = 1; i <= NPTS; ++i) {
        const float4 rr = s_p1[i - 1];
        const float  ui = s_u[i];
        bool ok0, ok1, ok2, ok3;
        #define ZCHK(K, VK, UMK, OK)                                           \
            { const float dx = rr.x - qx[K], dy = rr.y - qy[K], dz = rr.z - qz[K]; \
              const float red = (sqrtf(dx*dx + dy*dy + dz*dz) - ui) - VK;      \
              OK = ((UMK >> lane) & 1ull) && (red == 0.0f); }
        ZCHK(0, v0_, um0, ok0) ZCHK(1, v1_, um1, ok1)
        ZCHK(2, v2_, um2, ok2) ZCHK(3, v3_, um3, ok3)
        #undef ZCHK
        const int z = i - 1;
        unsigned long long mA;
        mA = __ballot(ok0);
        if (mA) { const int l = __builtin_ctzll(mA);
                  if (lane == l) { s_p[l +   1] = i; y0 = i; }
                  um0 &= ~(1ull << l); goto matched; }
        mA = __ballot(ok1);
        if (mA) { const int l = __builtin_ctzll(mA);
                  if (lane == l) { s_p[l +  65] = i; y1 = i; }
                  um1 &= ~(1ull << l); goto matched; }
        mA = __ballot(ok2);
        if (mA) { const int l = __builtin_ctzll(mA);
                  if (lane == l) { s_p[l + 129] = i; y2 = i; }
                  um2 &= ~(1ull << l); goto matched; }
        mA = __ballot(ok3);
        if (mA) { const int l = __builtin_ctzll(mA);
                  if (lane == l) { s_p[l + 193] = i; y3 = i; }
                  um3 &= ~(1ull << l); goto matched; }
        continue;
    matched:
        if      (z <  64) rm0 |= 1ull << z;
        else if (z < 128) rm1 |= 1ull << (z - 64);
        else if (z < 192) rm2 |= 1ull << (z - 128);
        else              rm3 |= 1ull << (z - 192);
    }

    // ---- Phase D: LAPJV augmenting row reduction (register worklist) ----
    {
        int qq0 = 0, qq1 = 0, qq2 = 0, qq3 = 0;   // ring buffer, slot s -> lane s&63, reg s>>6
        int qhead = 0, qtail = 0;
        // seed with all free rows (ascending)
        #pragma unroll
        for (int w = 0; w < 4; ++w) {
            unsigned long long fr = ~((w==0)?rm0:(w==1)?rm1:(w==2)?rm2:rm3);
            while (fr) {
                const int z = __builtin_ctzll(fr); fr &= fr - 1;
                const int row = w*64 + z + 1;
                const int slot = qtail & 255; ++qtail;
                if (lane == (slot & 63)) {
                    const int rg = slot >> 6;
                    if      (rg == 0) qq0 = row;
                    else if (rg == 1) qq1 = row;
                    else if (rg == 2) qq2 = row;
                    else              qq3 = row;
                }
            }
        }
        int budget = 1024;
        while (qhead != qtail && budget > 0) {
            --budget;
            // pop row i (register ring buffer, uniform index)
            const int slot = qhead & 255; ++qhead;
            const int rgp  = slot >> 6;
            const int qsel = (rgp == 0) ? qq0 : (rgp == 1) ? qq1 : (rgp == 2) ? qq2 : qq3;
            const int i    = __builtin_amdgcn_readlane(qsel, slot & 63);
            // row-i coords via register readlane from owner lane
            const int rzi = i - 1, rl = rzi & 63, rw = rzi >> 6;
            const float cxx = (rw==0)?r0.x:(rw==1)?r1.x:(rw==2)?r2.x:r3.x;
            const float cyy = (rw==0)?r0.y:(rw==1)?r1.y:(rw==2)?r2.y:r3.y;
            const float czz = (rw==0)?r0.z:(rw==1)?r1.z:(rw==2)?r2.z:r3.z;
            const float rx = readlane_f32(cxx, rl);
            const float ry = readlane_f32(cyy, rl);
            const float rz = readlane_f32(czz, rl);
            // reduced costs of own 4 columns; local (min1, argmin1, min2)
            float m1, m2; int c1;
            {
                const float rcA = sqrtf((rx-qx[0])*(rx-qx[0]) + (ry-qy[0])*(ry-qy[0]) + (rz-qz[0])*(rz-qz[0])) - v0_;
                const float rcB = sqrtf((rx-qx[1])*(rx-qx[1]) + (ry-qy[1])*(ry-qy[1]) + (rz-qz[1])*(rz-qz[1])) - v1_;
                const float rcC = sqrtf((rx-qx[2])*(rx-qx[2]) + (ry-qy[2])*(ry-qy[2]) + (rz-qz[2])*(rz-qz[2])) - v2_;
                const float rcD = sqrtf((rx-qx[3])*(rx-qx[3]) + (ry-qy[3])*(ry-qy[3]) + (rz-qz[3])*(rz-qz[3])) - v3_;
                m1 = rcA; c1 = lane + 1; m2 = FINF;
                if (rcB < m1) { m2 = m1; m1 = rcB; c1 = lane + 65;  } else m2 = fminf(m2, rcB);
                if (rcC < m1) { m2 = m1; m1 = rcC; c1 = lane + 129; } else m2 = fminf(m2, rcC);
                if (rcD < m1) { m2 = m1; m1 = rcD; c1 = lane + 193; } else m2 = fminf(m2, rcD);
            }
            dpp_min12_step<0x128, 0xF>(m1, c1, m2);   // row_ror:8
            dpp_min12_step<0x124, 0xF>(m1, c1, m2);   // row_ror:4
            dpp_min12_step<0x39,  0xF>(m1, c1, m2);   // quad_perm [1,2,3,0]
            dpp_min12_step<0x4E,  0xF>(m1, c1, m2);   // quad_perm [2,3,0,1]
            dpp_min12_step<0x142, 0xA>(m1, c1, m2);   // row_bcast:15
            dpp_min12_step<0x143, 0xC>(m1, c1, m2);   // row_bcast:31
            const float u1 = readlane_f32(m1, 63);
            const float u2 = readlane_f32(m2, 63);
            const int   j1 = __builtin_amdgcn_readlane(c1, 63);
            const int jz = j1 - 1, k4 = jz >> 6, l4 = jz & 63;
            const int i1 = __builtin_amdgcn_readlane(
                (k4==0)?y0:(k4==1)?y1:(k4==2)?y2:y3, l4);
            const float dv = u2 - u1;                 // >= 0
            if (lane == l4) {
                if      (k4 == 0) { v0_ -= dv; y0 = i; }
                else if (k4 == 1) { v1_ -= dv; y1 = i; }
                else if (k4 == 2) { v2_ -= dv; y2 = i; }
                else              { v3_ -= dv; y3 = i; }
            }
            if (lane == 0) { s_p[j1] = i; s_u[i] = u2; }
            { const int z = i - 1;                    // rm set i
              if      (z <  64) rm0 |= 1ull << z;
              else if (z < 128) rm1 |= 1ull << (z - 64);
              else if (z < 192) rm2 |= 1ull << (z - 128);
              else              rm3 |= 1ull << (z - 192); }
            if (i1 > 0) {                             // displaced row -> queue
                const int z = i1 - 1;
                if      (z <  64) rm0 &= ~(1ull << z);
                else if (z < 128) rm1 &= ~(1ull << (z - 64));
                else if (z < 192) rm2 &= ~(1ull << (z - 128));
                else              rm3 &= ~(1ull << (z - 192));
                const int ps = qtail & 255; ++qtail;
                if (lane == (ps & 63)) {
                    const int rg = ps >> 6;
                    if      (rg == 0) qq0 = i1;
                    else if (rg == 1) qq1 = i1;
                    else if (rg == 2) qq2 = i1;
                    else              qq3 = i1;
                }
            } else {                                   // column was free
                const unsigned long long m = ~(1ull << l4);
                if      (k4 == 0) um0 &= m;
                else if (k4 == 1) um1 &= m;
                else if (k4 == 2) um2 &= m;
                else              um3 &= m;
            }
        }
    }
    __syncthreads();

    // ---- Main: shortest augmenting path for each unmatched row ----
    for (int i = 1; i <= NPTS; ++i) {
        { const int z = i - 1;
          const unsigned long long r =
              (z < 64) ? rm0 : (z < 128) ? rm1 : (z < 192) ? rm2 : rm3;
          if ((r >> (z & 63)) & 1ull) continue; }

        float M0 = FINF, M1 = FINF, M2 = FINF, M3 = FINF;      // absolute minv
        int   wy0 = 0,   wy1 = 0,   wy2 = 0,   wy3 = 0;        // way
        bool  us0 = false, us1 = false, us2 = false, us3 = false;

        // path-start prefetch (p/u fixed until path end)
        const int   pj0 = s_p[lane + 1];
        const int   pj1 = s_p[lane + 65];
        const int   pj2 = s_p[lane + 129];
        const int   pj3 = s_p[lane + 193];
        const float up0 = s_u[pj0];
        const float up1 = s_u[pj1];
        const float up2 = s_u[pj2];
        const float up3 = s_u[pj3];
        const float4 pc0 = s_p1[(pj0 > 0 ? pj0 : 1) - 1];
        const float4 pc1 = s_p1[(pj1 > 0 ? pj1 : 1) - 1];
        const float4 pc2 = s_p1[(pj2 > 0 ? pj2 : 1) - 1];
        const float4 pc3 = s_p1[(pj3 > 0 ? pj3 : 1) - 1];
        if (lane == 0) s_p[0] = i;

        const float4 ri = s_p1[i - 1];
        float rx = ri.x, ry = ri.y, rz = ri.z;
        float D  = 0.0f;                // current min (absolute)
        float h  = 0.0f - s_u[i];       // h = D - u[i0]
        int   j0 = 0;
        int   jfin;

        for (;;) {
            // settle previous winner (flag only; its M already == settle-D)
            if (j0 > 0) {
                us0 = us0 || (j0 == lane + 1);
                us1 = us1 || (j0 == lane + 65);
                us2 = us2 || (j0 == lane + 129);
                us3 = us3 || (j0 == lane + 193);
            }

            // relax own free columns: cur_abs = c + (h - v_j)
            const float w0 = h - v0_, w1 = h - v1_, w2 = h - v2_, w3 = h - v3_;
            #define RELAX(K, WK)                                               \
                if (!us##K) {                                                  \
                    const float dx = rx - qx[K];                               \
                    const float dy = ry - qy[K];                               \
                    const float dz = rz - qz[K];                               \
                    const float c  = sqrtf(dx*dx + dy*dy + dz*dz);             \
                    const float cur = c + WK;                                  \
                    if (cur < M##K) { M##K = cur; wy##K = j0; }                \
                }
            RELAX(0, w0) RELAX(1, w1) RELAX(2, w2) RELAX(3, w3)
            #undef RELAX

            // lane-local min with index over own 4 columns
            float a01 = us0 ? FINF : M0; int c01 = lane + 1;
            if (!us1 && M1 < a01) { a01 = M1; c01 = lane + 65; }
            float a23 = us2 ? FINF : M2; int c23 = lane + 129;
            if (!us3 && M3 < a23) { a23 = M3; c23 = lane + 193; }
            float bl; int cl;
            if (a23 < a01) { bl = a23; cl = c23; } else { bl = a01; cl = c01; }

            // value-only 64-lane fmin (v_min_f32 propagates an operand bit-exactly)
            float bv = bl;
            bv = dpp_fmin_step<0x128, 0xF>(bv);   // row_ror:8
            bv = dpp_fmin_step<0x124, 0xF>(bv);   // row_ror:4
            bv = dpp_fmin_step<0x39,  0xF>(bv);   // quad_perm [1,2,3,0]
            bv = dpp_fmin_step<0x4E,  0xF>(bv);   // quad_perm [2,3,0,1]
            bv = dpp_fmin_step<0x142, 0xA>(bv);   // row_bcast:15
            bv = dpp_fmin_step<0x143, 0xC>(bv);   // row_bcast:31

            const float delta = readlane_f32(bv, 63);
            D = delta;                            // absolute: D_new = min M

            // winner index via one exact-equality ballot
            const unsigned long long mW = __ballot(bl == delta);
            const int lW = __builtin_ctzll(mW);
            const int j1 = __builtin_amdgcn_readlane(cl, lW);

            // terminate if j1 is an unmatched column
            const int jz = j1 - 1, k4 = jz >> 6, l4 = jz & 63;
            const unsigned long long um =
                (k4 == 0) ? um0 : (k4 == 1) ? um1 : (k4 == 2) ? um2 : um3;
            if ((um >> l4) & 1ull) { jfin = j1; break; }

            // payload: coords + u of j1's matched row via owner-lane readlane
            float sx, sy, sz, su;
            if      (k4 == 0) { sx = pc0.x; sy = pc0.y; sz = pc0.z; su = up0; }
            else if (k4 == 1) { sx = pc1.x; sy = pc1.y; sz = pc1.z; su = up1; }
            else if (k4 == 2) { sx = pc2.x; sy = pc2.y; sz = pc2.z; su = up2; }
            else              { sx = pc3.x; sy = pc3.y; sz = pc3.z; su = up3; }
            rx = readlane_f32(sx, l4);
            ry = readlane_f32(sy, l4);
            rz = readlane_f32(sz, l4);
            h  = D - readlane_f32(su, l4);
            j0 = j1;
        }

        // path end: dump ways, apply deferred potential updates
        s_way[lane + 1]   = wy0;
        s_way[lane + 65]  = wy1;
        s_way[lane + 129] = wy2;
        s_way[lane + 193] = wy3;
        if (us0) { const float adj = D - M0; v0_ -= adj; s_u[pj0] += adj; }
        if (us1) { const float adj = D - M1; v1_ -= adj; s_u[pj1] += adj; }
        if (us2) { const float adj = D - M2; v2_ -= adj; s_u[pj2] += adj; }
        if (us3) { const float adj = D - M3; v3_ -= adj; s_u[pj3] += adj; }
        if (lane == 0) s_u[i] += D;   // path root (settle-D = 0)
        __syncthreads();

        if (lane == 0) {               // augment alternating path (serial)
            int j = jfin;
            while (j != 0) { const int jp = s_way[j]; s_p[j] = s_p[jp]; j = jp; }
        }
        { const int jz = jfin - 1;
          const unsigned long long m = ~(1ull << (jz & 63));
          const int k4 = jz >> 6;
          if      (k4 == 0) um0 &= m;
          else if (k4 == 1) um1 &= m;
          else if (k4 == 2) um2 &= m;
          else              um3 &= m; }
        __syncthreads();
    }

    // mean matched cost for this batch (f64 sum of f32 costs, as reference)
    double s = 0.0;
    #pragma unroll
    for (int k = 0; k < 4; ++k) {
        const int idx = lane + 64 * k;
        const int r   = s_p[idx + 1] - 1;
        const float4 rr = s_p1[r];
        const float dx = rr.x - qx[k];
        const float dy = rr.y - qy[k];
        const float dz = rr.z - qz[k];
        s += (double)sqrtf(dx*dx + dy*dy + dz*dz);
    }
    #pragma unroll
    for (int off = 1; off < 64; off <<= 1) s += __shfl_xor(s, off, 64);
    if (lane == 0) batch_mean[b] = s / (double)NPTS;
}

__global__ void emd_finalize_kernel(const double* __restrict__ bm,
                                    float* __restrict__ out)
{
    double s = 0.0;
    #pragma unroll
    for (int i = 0; i < NBATCH; ++i) s += bm[i];
    out[0] = (float)(s / (double)NBATCH);
}

extern "C" void kernel_launch(void* const* d_in, const int* in_sizes, int n_in,
                              void* d_out, int out_size, void* d_ws, size_t ws_size,
                              hipStream_t stream)
{
    const float* p1 = (const float*)d_in[0];   // [B, N, 3] f32
    const float* p2 = (const float*)d_in[1];   // [B, N, 3] f32
    double* bm = (double*)d_ws;                // 32 doubles of scratch

    emd_hungarian_wave<<<NBATCH, 64, 0, stream>>>(p1, p2, bm);
    emd_finalize_kernel<<<1, 1, 0, stream>>>(bm, (float*)d_out);
}

// Round 10
// 2758.569 us; speedup vs baseline: 1.1255x; 1.1255x over previous
//
#include <hip/hip_runtime.h>
#include <hip/hip_bf16.h>
#include <math.h>

// EMD loss via exact Hungarian (Jonker-Volgenant shortest augmenting path).
// B=32, N=256, D=3. ONE WAVE per batch, 4 columns per lane.
// Round-10: revert ARR (round-9 regression: tail paths dominate, warm-start
// quality is not the lever). Base = validated round-7 structure (2940us,
// absmax 0.0) + per-settle chain micro-opts:
//   - settle loop unrolled x2 (halve loop-branch overhead)
//   - packed `used` bitmask usm, branchless update (1 cmp + masked-or)
//   - matched-row u packed into pc.w (one float4 payload stream)
// Selection/tie semantics identical to round 7: strict < local min prefers
// lower K; ballot-ctz picks lowest lane; exact-equality winner recovery.

#define NPTS   256
#define NBATCH 32
#define FINF   (__builtin_inff())

// one DPP fmin step on f32; masked-out lanes combine with +INF (identity)
template<int CTRL, int ROWM>
__device__ __forceinline__ float dpp_fmin_step(float bv) {
    const int s = __float_as_int(bv);
    const int f = __float_as_int(FINF);
    const int w = __builtin_amdgcn_update_dpp(f, s, CTRL, ROWM, 0xF, false);
    return fminf(bv, __int_as_float(w));
}

__device__ __forceinline__ float readlane_f32(float x, int l) {
    return __uint_as_float((unsigned)__builtin_amdgcn_readlane((int)__float_as_uint(x), l));
}

__global__ __launch_bounds__(64) void emd_hungarian_wave(
    const float* __restrict__ p1,
    const float* __restrict__ p2,
    double* __restrict__ batch_mean)
{
    const int b    = blockIdx.x;
    const int lane = threadIdx.x;

    __shared__ float4 s_p1[NPTS];       // p1 points (immutable after setup)
    __shared__ float4 s_q [NPTS];       // p2 points (immutable after setup)
    __shared__ float  s_u [NPTS + 1];   // row potentials (f32)
    __shared__ int    s_p [NPTS + 1];   // p[j] = row matched to column j
    __shared__ int    s_way[NPTS + 1];  // back pointers

    const float* p1b = p1 + (size_t)b * NPTS * 3;
    const float* p2b = p2 + (size_t)b * NPTS * 3;

    float qx[4], qy[4], qz[4];
    #pragma unroll
    for (int k = 0; k < 4; ++k) {
        const int idx = lane + 64 * k;
        s_p1[idx] = make_float4(p1b[idx*3+0], p1b[idx*3+1], p1b[idx*3+2], 0.0f);
        const float a = p2b[idx*3+0], c = p2b[idx*3+1], d = p2b[idx*3+2];
        s_q[idx] = make_float4(a, c, d, 0.0f);
        qx[k] = a; qy[k] = c; qz[k] = d;
        s_p[idx + 1] = 0;
    }
    if (lane == 0) { s_u[0] = 0.0f; s_p[0] = 0; }
    __syncthreads();

    // ---- Phase A: row reduction u[r] = min_j c(r,j) (lane owns 4 rows) ----
    {
        const float4 r0 = s_p1[lane], r1 = s_p1[lane+64],
                     r2 = s_p1[lane+128], r3 = s_p1[lane+192];
        float m0 = FINF, m1 = FINF, m2 = FINF, m3 = FINF;   // min squared dist
        for (int j = 0; j < NPTS; ++j) {
            const float4 q = s_q[j];
            #define D2(R) ((R.x-q.x)*(R.x-q.x) + (R.y-q.y)*(R.y-q.y) + (R.z-q.z)*(R.z-q.z))
            m0 = fminf(m0, D2(r0)); m1 = fminf(m1, D2(r1));
            m2 = fminf(m2, D2(r2)); m3 = fminf(m3, D2(r3));
            #undef D2
        }
        // sqrt is monotone: min_j sqrtf(d2) == sqrtf(min_j d2) exactly
        s_u[lane +   1] = sqrtf(m0);
        s_u[lane +  65] = sqrtf(m1);
        s_u[lane + 129] = sqrtf(m2);
        s_u[lane + 193] = sqrtf(m3);
    }
    __syncthreads();

    // ---- Phase B: column reduction v[j] = min_i (c(i,j) - u[i]) ----
    float v0_ = FINF, v1_ = FINF, v2_ = FINF, v3_ = FINF;
    for (int i2 = 0; i2 < NPTS; ++i2) {
        const float4 rr = s_p1[i2];
        const float  ui = s_u[i2 + 1];
        #define CAND(K, VK)                                                    \
            { const float dx = rr.x - qx[K], dy = rr.y - qy[K], dz = rr.z - qz[K]; \
              const float cd = sqrtf(dx*dx + dy*dy + dz*dz) - ui;              \
              VK = fminf(VK, cd); }
        CAND(0, v0_) CAND(1, v1_) CAND(2, v2_) CAND(3, v3_)
        #undef CAND
    }

    // ---- Phase C: greedy matching on exact zeros of reduced cost ----
    unsigned long long um0 = ~0ull, um1 = ~0ull, um2 = ~0ull, um3 = ~0ull; // unmatched cols
    unsigned long long rm0 = 0, rm1 = 0, rm2 = 0, rm3 = 0;                 // matched rows
    for (int i = 1; i <= NPTS; ++i) {
        const float4 rr = s_p1[i - 1];
        const float  ui = s_u[i];
        bool ok0, ok1, ok2, ok3;
        #define ZCHK(K, VK, UMK, OK)                                           \
            { const float dx = rr.x - qx[K], dy = rr.y - qy[K], dz = rr.z - qz[K]; \
              const float red = (sqrtf(dx*dx + dy*dy + dz*dz) - ui) - VK;      \
              OK = ((UMK >> lane) & 1ull) && (red == 0.0f); }
        ZCHK(0, v0_, um0, ok0) ZCHK(1, v1_, um1, ok1)
        ZCHK(2, v2_, um2, ok2) ZCHK(3, v3_, um3, ok3)
        #undef ZCHK
        const int z = i - 1;
        unsigned long long mA;
        mA = __ballot(ok0);
        if (mA) { const int l = __builtin_ctzll(mA); if (lane == l) s_p[l +   1] = i;
                  um0 &= ~(1ull << l); goto matched; }
        mA = __ballot(ok1);
        if (mA) { const int l = __builtin_ctzll(mA); if (lane == l) s_p[l +  65] = i;
                  um1 &= ~(1ull << l); goto matched; }
        mA = __ballot(ok2);
        if (mA) { const int l = __builtin_ctzll(mA); if (lane == l) s_p[l + 129] = i;
                  um2 &= ~(1ull << l); goto matched; }
        mA = __ballot(ok3);
        if (mA) { const int l = __builtin_ctzll(mA); if (lane == l) s_p[l + 193] = i;
                  um3 &= ~(1ull << l); goto matched; }
        continue;
    matched:
        if      (z <  64) rm0 |= 1ull << z;
        else if (z < 128) rm1 |= 1ull << (z - 64);
        else if (z < 192) rm2 |= 1ull << (z - 128);
        else              rm3 |= 1ull << (z - 192);
    }
    __syncthreads();

    // ---- Main: shortest augmenting path for each unmatched row ----
    for (int i = 1; i <= NPTS; ++i) {
        { const int z = i - 1;
          const unsigned long long r =
              (z < 64) ? rm0 : (z < 128) ? rm1 : (z < 192) ? rm2 : rm3;
          if ((r >> (z & 63)) & 1ull) continue; }

        float M0 = FINF, M1 = FINF, M2 = FINF, M3 = FINF;      // absolute minv
        int   wy0 = 0,   wy1 = 0,   wy2 = 0,   wy3 = 0;        // way
        unsigned usm = 0u;                                     // settled bits K=0..3

        // path-start prefetch (p/u fixed until path end); u packed in pc.w
        const int   pj0 = s_p[lane + 1];
        const int   pj1 = s_p[lane + 65];
        const int   pj2 = s_p[lane + 129];
        const int   pj3 = s_p[lane + 193];
        float4 pc0 = s_p1[(pj0 > 0 ? pj0 : 1) - 1]; pc0.w = s_u[pj0];
        float4 pc1 = s_p1[(pj1 > 0 ? pj1 : 1) - 1]; pc1.w = s_u[pj1];
        float4 pc2 = s_p1[(pj2 > 0 ? pj2 : 1) - 1]; pc2.w = s_u[pj2];
        float4 pc3 = s_p1[(pj3 > 0 ? pj3 : 1) - 1]; pc3.w = s_u[pj3];
        if (lane == 0) s_p[0] = i;

        const float4 ri = s_p1[i - 1];
        float rx = ri.x, ry = ri.y, rz = ri.z;
        float D  = 0.0f;                // current min (absolute)
        float h  = 0.0f - s_u[i];       // h = D - u[i0]
        int   j0 = 0;
        int   jfin;

        // one settle + advance; `break` exits the enclosing for(;;)
        #define SETTLE_STEP()                                                  \
        {                                                                      \
            /* branchless settle-flag update for previous winner j0 */         \
            const unsigned jp  = (unsigned)(j0 - 1);                           \
            const bool     hit = (j0 != 0) && ((int)(jp & 63u) == lane);       \
            const unsigned bitp = 1u << ((jp >> 6) & 31u);                     \
            if (hit) usm |= bitp;                                              \
            const bool f0 = !(usm & 1u), f1 = !(usm & 2u);                     \
            const bool f2 = !(usm & 4u), f3 = !(usm & 8u);                     \
            /* relax own free columns: cur = c + (h - v_j) */                  \
            const float w0 = h - v0_, w1 = h - v1_, w2 = h - v2_, w3 = h - v3_;\
            if (f0) { const float dx = rx-qx[0], dy = ry-qy[0], dz = rz-qz[0]; \
                      const float cur = sqrtf(dx*dx+dy*dy+dz*dz) + w0;         \
                      if (cur < M0) { M0 = cur; wy0 = j0; } }                  \
            if (f1) { const float dx = rx-qx[1], dy = ry-qy[1], dz = rz-qz[1]; \
                      const float cur = sqrtf(dx*dx+dy*dy+dz*dz) + w1;         \
                      if (cur < M1) { M1 = cur; wy1 = j0; } }                  \
            if (f2) { const float dx = rx-qx[2], dy = ry-qy[2], dz = rz-qz[2]; \
                      const float cur = sqrtf(dx*dx+dy*dy+dz*dz) + w2;         \
                      if (cur < M2) { M2 = cur; wy2 = j0; } }                  \
            if (f3) { const float dx = rx-qx[3], dy = ry-qy[3], dz = rz-qz[3]; \
                      const float cur = sqrtf(dx*dx+dy*dy+dz*dz) + w3;         \
                      if (cur < M3) { M3 = cur; wy3 = j0; } }                  \
            /* lane-local min with index (strict <, prefers lower K) */        \
            float a01 = f0 ? M0 : FINF; int c01 = lane + 1;                    \
            if (f1 && M1 < a01) { a01 = M1; c01 = lane + 65; }                 \
            float a23 = f2 ? M2 : FINF; int c23 = lane + 129;                  \
            if (f3 && M3 < a23) { a23 = M3; c23 = lane + 193; }                \
            float bl; int cl;                                                  \
            if (a23 < a01) { bl = a23; cl = c23; } else { bl = a01; cl = c01; }\
            /* value-only 64-lane fmin (bit-exact operand propagation) */      \
            float bv = bl;                                                     \
            bv = dpp_fmin_step<0x128, 0xF>(bv);   /* row_ror:8  */             \
            bv = dpp_fmin_step<0x124, 0xF>(bv);   /* row_ror:4  */             \
            bv = dpp_fmin_step<0x39,  0xF>(bv);   /* quad_perm [1,2,3,0] */    \
            bv = dpp_fmin_step<0x4E,  0xF>(bv);   /* quad_perm [2,3,0,1] */    \
            bv = dpp_fmin_step<0x142, 0xA>(bv);   /* row_bcast:15 */           \
            bv = dpp_fmin_step<0x143, 0xC>(bv);   /* row_bcast:31 */           \
            const float delta = readlane_f32(bv, 63);                          \
            D = delta;                                                         \
            /* winner via one exact-equality ballot (lowest lane on ties) */   \
            const unsigned long long mW = __ballot(bl == delta);               \
            const int lW = __builtin_ctzll(mW);                                \
            const int j1 = __builtin_amdgcn_readlane(cl, lW);                  \
            /* terminate if j1 is an unmatched column */                       \
            const int jz = j1 - 1, k4 = jz >> 6, l4 = jz & 63;                 \
            const unsigned long long um =                                      \
                (k4 == 0) ? um0 : (k4 == 1) ? um1 : (k4 == 2) ? um2 : um3;     \
            if ((um >> l4) & 1ull) { jfin = j1; break; }                       \
            /* payload: coords + u (pc.w) of j1's matched row */               \
            float4 sc;                                                         \
            if      (k4 == 0) sc = pc0;                                        \
            else if (k4 == 1) sc = pc1;                                        \
            else if (k4 == 2) sc = pc2;                                        \
            else              sc = pc3;                                        \
            rx = readlane_f32(sc.x, l4);                                       \
            ry = readlane_f32(sc.y, l4);                                       \
            rz = readlane_f32(sc.z, l4);                                       \
            h  = D - readlane_f32(sc.w, l4);                                   \
            j0 = j1;                                                           \
        }

        for (;;) {
            SETTLE_STEP();
            SETTLE_STEP();
        }
        #undef SETTLE_STEP

        // path end: dump ways, apply deferred potential updates
        s_way[lane + 1]   = wy0;
        s_way[lane + 65]  = wy1;
        s_way[lane + 129] = wy2;
        s_way[lane + 193] = wy3;
        if (usm & 1u) { const float adj = D - M0; v0_ -= adj; s_u[pj0] += adj; }
        if (usm & 2u) { const float adj = D - M1; v1_ -= adj; s_u[pj1] += adj; }
        if (usm & 4u) { const float adj = D - M2; v2_ -= adj; s_u[pj2] += adj; }
        if (usm & 8u) { const float adj = D - M3; v3_ -= adj; s_u[pj3] += adj; }
        if (lane == 0) s_u[i] += D;   // path root (settle-D = 0)
        __syncthreads();

        if (lane == 0) {               // augment alternating path (serial)
            int j = jfin;
            while (j != 0) { const int jp = s_way[j]; s_p[j] = s_p[jp]; j = jp; }
        }
        { const int jz = jfin - 1;
          const unsigned long long m = ~(1ull << (jz & 63));
          const int k4 = jz >> 6;
          if      (k4 == 0) um0 &= m;
          else if (k4 == 1) um1 &= m;
          else if (k4 == 2) um2 &= m;
          else              um3 &= m; }
        __syncthreads();
    }

    // mean matched cost for this batch (f64 sum of f32 costs, as reference)
    double s = 0.0;
    #pragma unroll
    for (int k = 0; k < 4; ++k) {
        const int idx = lane + 64 * k;
        const int r   = s_p[idx + 1] - 1;
        const float4 rr = s_p1[r];
        const float dx = rr.x - qx[k];
        const float dy = rr.y - qy[k];
        const float dz = rr.z - qz[k];
        s += (double)sqrtf(dx*dx + dy*dy + dz*dz);
    }
    #pragma unroll
    for (int off = 1; off < 64; off <<= 1) s += __shfl_xor(s, off, 64);
    if (lane == 0) batch_mean[b] = s / (double)NPTS;
}

__global__ void emd_finalize_kernel(const double* __restrict__ bm,
                                    float* __restrict__ out)
{
    double s = 0.0;
    #pragma unroll
    for (int i = 0; i < NBATCH; ++i) s += bm[i];
    out[0] = (float)(s / (double)NBATCH);
}

extern "C" void kernel_launch(void* const* d_in, const int* in_sizes, int n_in,
                              void* d_out, int out_size, void* d_ws, size_t ws_size,
                              hipStream_t stream)
{
    const float* p1 = (const float*)d_in[0];   // [B, N, 3] f32
    const float* p2 = (const float*)d_in[1];   // [B, N, 3] f32
    double* bm = (double*)d_ws;                // 32 doubles of scratch

    emd_hungarian_wave<<<NBATCH, 64, 0, stream>>>(p1, p2, bm);
    emd_finalize_kernel<<<1, 1, 0, stream>>>(bm, (float*)d_out);
}

// Round 12
// 2540.507 us; speedup vs baseline: 1.2221x; 1.0858x over previous
//
#include <hip/hip_runtime.h>
#include <hip/hip_bf16.h>
#include <math.h>

// EMD loss via exact Hungarian (Jonker-Volgenant shortest augmenting path).
// B=32, N=256, D=3. ONE WAVE per batch, 4 columns per lane.
// Round-11/12: packed-key argmin. All labels M >= 0 (feasible frozen duals,
// fmaxf clamp) => positive f32 bits are u32-monotone; key = (bits(M)&~3)|K
// carries the column slot K through a u32-min DPP reduce for free. Winner
// lane via one ballot on the local key; j1 = lane + 1 + 64*K is pure SALU
// (no readlane(cl,lW) on the chain). Selection perturbed only within 3-ulp
// ties; final mean recomputes true distances, so output error
// <= suboptimality/8192 (~1e-9).

#define NPTS   256
#define NBATCH 32
#define FINF   (__builtin_inff())

// one DPP u32-min step; masked-out lanes combine with 0xFFFFFFFF (identity)
template<int CTRL, int ROWM>
__device__ __forceinline__ unsigned dpp_umin_step(unsigned bv) {
    const unsigned w = (unsigned)__builtin_amdgcn_update_dpp(
        (int)0xFFFFFFFFu, (int)bv, CTRL, ROWM, 0xF, false);
    return (bv < w) ? bv : w;
}

__device__ __forceinline__ float readlane_f32(float x, int l) {
    return __uint_as_float((unsigned)__builtin_amdgcn_readlane((int)__float_as_uint(x), l));
}

__global__ __launch_bounds__(64) void emd_hungarian_wave(
    const float* __restrict__ p1,
    const float* __restrict__ p2,
    double* __restrict__ batch_mean)
{
    const int b    = blockIdx.x;
    const int lane = threadIdx.x;

    __shared__ float4 s_p1[NPTS];       // p1 points (immutable after setup)
    __shared__ float4 s_q [NPTS];       // p2 points (immutable after setup)
    __shared__ float  s_u [NPTS + 1];   // row potentials (f32)
    __shared__ int    s_p [NPTS + 1];   // p[j] = row matched to column j
    __shared__ int    s_way[NPTS + 1];  // back pointers

    const float* p1b = p1 + (size_t)b * NPTS * 3;
    const float* p2b = p2 + (size_t)b * NPTS * 3;

    float qx[4], qy[4], qz[4];
    #pragma unroll
    for (int k = 0; k < 4; ++k) {
        const int idx = lane + 64 * k;
        s_p1[idx] = make_float4(p1b[idx*3+0], p1b[idx*3+1], p1b[idx*3+2], 0.0f);
        const float a = p2b[idx*3+0], c = p2b[idx*3+1], d = p2b[idx*3+2];
        s_q[idx] = make_float4(a, c, d, 0.0f);
        qx[k] = a; qy[k] = c; qz[k] = d;
        s_p[idx + 1] = 0;
    }
    if (lane == 0) { s_u[0] = 0.0f; s_p[0] = 0; }
    __syncthreads();

    // ---- Phase A: row reduction u[r] = min_j c(r,j) (lane owns 4 rows) ----
    {
        const float4 r0 = s_p1[lane], r1 = s_p1[lane+64],
                     r2 = s_p1[lane+128], r3 = s_p1[lane+192];
        float m0 = FINF, m1 = FINF, m2 = FINF, m3 = FINF;   // min squared dist
        for (int j = 0; j < NPTS; ++j) {
            const float4 q = s_q[j];
            #define D2(R) ((R.x-q.x)*(R.x-q.x) + (R.y-q.y)*(R.y-q.y) + (R.z-q.z)*(R.z-q.z))
            m0 = fminf(m0, D2(r0)); m1 = fminf(m1, D2(r1));
            m2 = fminf(m2, D2(r2)); m3 = fminf(m3, D2(r3));
            #undef D2
        }
        // sqrt is monotone: min_j sqrtf(d2) == sqrtf(min_j d2) exactly
        s_u[lane +   1] = sqrtf(m0);
        s_u[lane +  65] = sqrtf(m1);
        s_u[lane + 129] = sqrtf(m2);
        s_u[lane + 193] = sqrtf(m3);
    }
    __syncthreads();

    // ---- Phase B: column reduction v[j] = min_i (c(i,j) - u[i]) ----
    float v0_ = FINF, v1_ = FINF, v2_ = FINF, v3_ = FINF;
    for (int i2 = 0; i2 < NPTS; ++i2) {
        const float4 rr = s_p1[i2];
        const float  ui = s_u[i2 + 1];
        #define CAND(K, VK)                                                    \
            { const float dx = rr.x - qx[K], dy = rr.y - qy[K], dz = rr.z - qz[K]; \
              const float cd = sqrtf(dx*dx + dy*dy + dz*dz) - ui;              \
              VK = fminf(VK, cd); }
        CAND(0, v0_) CAND(1, v1_) CAND(2, v2_) CAND(3, v3_)
        #undef CAND
    }

    // ---- Phase C: greedy matching on exact zeros of reduced cost ----
    unsigned long long um0 = ~0ull, um1 = ~0ull, um2 = ~0ull, um3 = ~0ull; // unmatched cols
    unsigned long long rm0 = 0, rm1 = 0, rm2 = 0, rm3 = 0;                 // matched rows
    for (int i = 1; i <= NPTS; ++i) {
        const float4 rr = s_p1[i - 1];
        const float  ui = s_u[i];
        bool ok0, ok1, ok2, ok3;
        #define ZCHK(K, VK, UMK, OK)                                           \
            { const float dx = rr.x - qx[K], dy = rr.y - qy[K], dz = rr.z - qz[K]; \
              const float red = (sqrtf(dx*dx + dy*dy + dz*dz) - ui) - VK;      \
              OK = ((UMK >> lane) & 1ull) && (red == 0.0f); }
        ZCHK(0, v0_, um0, ok0) ZCHK(1, v1_, um1, ok1)
        ZCHK(2, v2_, um2, ok2) ZCHK(3, v3_, um3, ok3)
        #undef ZCHK
        const int z = i - 1;
        unsigned long long mA;
        mA = __ballot(ok0);
        if (mA) { const int l = __builtin_ctzll(mA); if (lane == l) s_p[l +   1] = i;
                  um0 &= ~(1ull << l); goto matched; }
        mA = __ballot(ok1);
        if (mA) { const int l = __builtin_ctzll(mA); if (lane == l) s_p[l +  65] = i;
                  um1 &= ~(1ull << l); goto matched; }
        mA = __ballot(ok2);
        if (mA) { const int l = __builtin_ctzll(mA); if (lane == l) s_p[l + 129] = i;
                  um2 &= ~(1ull << l); goto matched; }
        mA = __ballot(ok3);
        if (mA) { const int l = __builtin_ctzll(mA); if (lane == l) s_p[l + 193] = i;
                  um3 &= ~(1ull << l); goto matched; }
        continue;
    matched:
        if      (z <  64) rm0 |= 1ull << z;
        else if (z < 128) rm1 |= 1ull << (z - 64);
        else if (z < 192) rm2 |= 1ull << (z - 128);
        else              rm3 |= 1ull << (z - 192);
    }
    __syncthreads();

    // ---- Main: shortest augmenting path for each unmatched row ----
    for (int i = 1; i <= NPTS; ++i) {
        { const int z = i - 1;
          const unsigned long long r =
              (z < 64) ? rm0 : (z < 128) ? rm1 : (z < 192) ? rm2 : rm3;
          if ((r >> (z & 63)) & 1ull) continue; }

        float M0 = FINF, M1 = FINF, M2 = FINF, M3 = FINF;      // absolute minv
        int   wy0 = 0,   wy1 = 0,   wy2 = 0,   wy3 = 0;        // way
        unsigned usm = 0u;                                     // settled bits K=0..3

        // path-start prefetch (p/u fixed until path end); u packed in pc.w
        const int   pj0 = s_p[lane + 1];
        const int   pj1 = s_p[lane + 65];
        const int   pj2 = s_p[lane + 129];
        const int   pj3 = s_p[lane + 193];
        float4 pc0 = s_p1[(pj0 > 0 ? pj0 : 1) - 1]; pc0.w = s_u[pj0];
        float4 pc1 = s_p1[(pj1 > 0 ? pj1 : 1) - 1]; pc1.w = s_u[pj1];
        float4 pc2 = s_p1[(pj2 > 0 ? pj2 : 1) - 1]; pc2.w = s_u[pj2];
        float4 pc3 = s_p1[(pj3 > 0 ? pj3 : 1) - 1]; pc3.w = s_u[pj3];
        if (lane == 0) s_p[0] = i;

        const float4 ri = s_p1[i - 1];
        float rx = ri.x, ry = ri.y, rz = ri.z;
        float D  = 0.0f;                // current min (absolute)
        float h  = 0.0f - s_u[i];       // h = D - u[i0]
        int   j0 = 0;
        int   jfin;

        // one settle + advance; `break` exits the enclosing for(;;)
        #define SETTLE_STEP()                                                  \
        {                                                                      \
            /* branchless settle-flag update for previous winner j0 */         \
            const unsigned jp  = (unsigned)(j0 - 1);                           \
            const bool     hit = (j0 != 0) && ((int)(jp & 63u) == lane);       \
            const unsigned bitp = 1u << ((jp >> 6) & 31u);                     \
            if (hit) usm |= bitp;                                              \
            const bool f0 = !(usm & 1u), f1 = !(usm & 2u);                     \
            const bool f2 = !(usm & 4u), f3 = !(usm & 8u);                     \
            /* relax own free columns: cur = c + (h - v_j), clamped >= 0 */    \
            const float w0 = h - v0_, w1 = h - v1_, w2 = h - v2_, w3 = h - v3_;\
            if (f0) { const float dx = rx-qx[0], dy = ry-qy[0], dz = rz-qz[0]; \
                      const float cur = fmaxf(sqrtf(dx*dx+dy*dy+dz*dz) + w0, 0.0f); \
                      if (cur < M0) { M0 = cur; wy0 = j0; } }                  \
            if (f1) { const float dx = rx-qx[1], dy = ry-qy[1], dz = rz-qz[1]; \
                      const float cur = fmaxf(sqrtf(dx*dx+dy*dy+dz*dz) + w1, 0.0f); \
                      if (cur < M1) { M1 = cur; wy1 = j0; } }                  \
            if (f2) { const float dx = rx-qx[2], dy = ry-qy[2], dz = rz-qz[2]; \
                      const float cur = fmaxf(sqrtf(dx*dx+dy*dy+dz*dz) + w2, 0.0f); \
                      if (cur < M2) { M2 = cur; wy2 = j0; } }                  \
            if (f3) { const float dx = rx-qx[3], dy = ry-qy[3], dz = rz-qz[3]; \
                      const float cur = fmaxf(sqrtf(dx*dx+dy*dy+dz*dz) + w3, 0.0f); \
                      if (cur < M3) { M3 = cur; wy3 = j0; } }                  \
            /* packed keys: (bits(M) & ~3) | K ; settled -> u32 max */         \
            const unsigned pk0 = f0 ? ((__float_as_uint(M0) & ~3u) | 0u) : 0xFFFFFFFFu; \
            const unsigned pk1 = f1 ? ((__float_as_uint(M1) & ~3u) | 1u) : 0xFFFFFFFFu; \
            const unsigned pk2 = f2 ? ((__float_as_uint(M2) & ~3u) | 2u) : 0xFFFFFFFFu; \
            const unsigned pk3 = f3 ? ((__float_as_uint(M3) & ~3u) | 3u) : 0xFFFFFFFFu; \
            const unsigned pa = (pk0 < pk1) ? pk0 : pk1;                       \
            const unsigned pb = (pk2 < pk3) ? pk2 : pk3;                       \
            const unsigned pl = (pa < pb) ? pa : pb;                           \
            /* 64-lane u32-min reduce (carries K for free) */                  \
            unsigned pv = pl;                                                  \
            pv = dpp_umin_step<0x128, 0xF>(pv);   /* row_ror:8  */             \
            pv = dpp_umin_step<0x124, 0xF>(pv);   /* row_ror:4  */             \
            pv = dpp_umin_step<0x39,  0xF>(pv);   /* quad_perm [1,2,3,0] */    \
            pv = dpp_umin_step<0x4E,  0xF>(pv);   /* quad_perm [2,3,0,1] */    \
            pv = dpp_umin_step<0x142, 0xA>(pv);   /* row_bcast:15 */           \
            pv = dpp_umin_step<0x143, 0xC>(pv);   /* row_bcast:31 */           \
            const unsigned pw = (unsigned)__builtin_amdgcn_readlane((int)pv, 63); \
            const float delta = __uint_as_float(pw & ~3u);                     \
            D = delta;                                                         \
            /* winner lane via one ballot; j1 from (lane, K) -- pure SALU */   \
            const unsigned long long mW = __ballot(pl == pw);                  \
            const int lW = __builtin_ctzll(mW);                                \
            const int kW = (int)(pw & 3u);                                     \
            const int j1 = lW + 1 + (kW << 6);                                 \
            /* terminate if j1 is an unmatched column */                       \
            const unsigned long long um =                                      \
                (kW == 0) ? um0 : (kW == 1) ? um1 : (kW == 2) ? um2 : um3;     \
            if ((um >> lW) & 1ull) { jfin = j1; break; }                       \
            /* payload: coords + u (pc.w) of j1's matched row */               \
            float4 sc;                                                         \
            if      (kW == 0) sc = pc0;                                        \
            else if (kW == 1) sc = pc1;                                        \
            else if (kW == 2) sc = pc2;                                        \
            else              sc = pc3;                                        \
            rx = readlane_f32(sc.x, lW);                                       \
            ry = readlane_f32(sc.y, lW);                                       \
            rz = readlane_f32(sc.z, lW);                                       \
            h  = D - readlane_f32(sc.w, lW);                                   \
            j0 = j1;                                                           \
        }

        for (;;) {
            SETTLE_STEP();
            SETTLE_STEP();
        }
        #undef SETTLE_STEP

        // path end: dump ways, apply deferred potential updates
        s_way[lane + 1]   = wy0;
        s_way[lane + 65]  = wy1;
        s_way[lane + 129] = wy2;
        s_way[lane + 193] = wy3;
        if (usm & 1u) { const float adj = D - M0; v0_ -= adj; s_u[pj0] += adj; }
        if (usm & 2u) { const float adj = D - M1; v1_ -= adj; s_u[pj1] += adj; }
        if (usm & 4u) { const float adj = D - M2; v2_ -= adj; s_u[pj2] += adj; }
        if (usm & 8u) { const float adj = D - M3; v3_ -= adj; s_u[pj3] += adj; }
        if (lane == 0) s_u[i] += D;   // path root (settle-D = 0)
        __syncthreads();

        if (lane == 0) {               // augment alternating path (serial)
            int j = jfin;
            while (j != 0) { const int jp = s_way[j]; s_p[j] = s_p[jp]; j = jp; }
        }
        { const int jz = jfin - 1;
          const unsigned long long m = ~(1ull << (jz & 63));
          const int k4 = jz >> 6;
          if      (k4 == 0) um0 &= m;
          else if (k4 == 1) um1 &= m;
          else if (k4 == 2) um2 &= m;
          else              um3 &= m; }
        __syncthreads();
    }

    // mean matched cost for this batch (f64 sum of f32 costs, as reference)
    double s = 0.0;
    #pragma unroll
    for (int k = 0; k < 4; ++k) {
        const int idx = lane + 64 * k;
        const int r   = s_p[idx + 1] - 1;
        const float4 rr = s_p1[r];
        const float dx = rr.x - qx[k];
        const float dy = rr.y - qy[k];
        const float dz = rr.z - qz[k];
        s += (double)sqrtf(dx*dx + dy*dy + dz*dz);
    }
    #pragma unroll
    for (int off = 1; off < 64; off <<= 1) s += __shfl_xor(s, off, 64);
    if (lane == 0) batch_mean[b] = s / (double)NPTS;
}

__global__ void emd_finalize_kernel(const double* __restrict__ bm,
                                    float* __restrict__ out)
{
    double s = 0.0;
    #pragma unroll
    for (int i = 0; i < NBATCH; ++i) s += bm[i];
    out[0] = (float)(s / (double)NBATCH);
}

extern "C" void kernel_launch(void* const* d_in, const int* in_sizes, int n_in,
                              void* d_out, int out_size, void* d_ws, size_t ws_size,
                              hipStream_t stream)
{
    const float* p1 = (const float*)d_in[0];   // [B, N, 3] f32
    const float* p2 = (const float*)d_in[1];   // [B, N, 3] f32
    double* bm = (double*)d_ws;                // 32 doubles of scratch

    emd_hungarian_wave<<<NBATCH, 64, 0, stream>>>(p1, p2, bm);
    emd_finalize_kernel<<<1, 1, 0, stream>>>(bm, (float*)d_out);
}

// Round 13
// 2515.232 us; speedup vs baseline: 1.2344x; 1.0100x over previous
//
#include <hip/hip_runtime.h>
#include <hip/hip_bf16.h>
#include <math.h>

// EMD loss via exact Hungarian (Jonker-Volgenant shortest augmenting path).
// B=32, N=256, D=3. ONE WAVE per batch, 4 columns per lane.
// Round-13 change vs validated round-12 kernel (2540us, absmax 0.0):
// packed key now carries a matched-preference bit and the termination flag:
//   key = (bits(M) & ~7) | (matched?4:0) | K
// - u32-min prefers UNMATCHED columns on 7-ulp ties -> immediate path
//   termination on near-ties (saves all remaining settles of that path).
// - termination test = bit 2 of the reduced key (1 SALU), replacing the
//   4-way u64 select + shift chain on the loop-carried path.
// matched-bit is frozen during a path (um only changes at augment), so it
// folds into per-path constants mb_K; the pack stays one v_and_or_b32.
// Perturbation: selection changes only within 7-ulp ties (~8e-7 relative);
// final mean recomputes true f32 distances -> output error ~1e-8.

#define NPTS   256
#define NBATCH 32
#define FINF   (__builtin_inff())

// one DPP u32-min step; masked-out lanes combine with 0xFFFFFFFF (identity)
template<int CTRL, int ROWM>
__device__ __forceinline__ unsigned dpp_umin_step(unsigned bv) {
    const unsigned w = (unsigned)__builtin_amdgcn_update_dpp(
        (int)0xFFFFFFFFu, (int)bv, CTRL, ROWM, 0xF, false);
    return (bv < w) ? bv : w;
}

__device__ __forceinline__ float readlane_f32(float x, int l) {
    return __uint_as_float((unsigned)__builtin_amdgcn_readlane((int)__float_as_uint(x), l));
}

__global__ __launch_bounds__(64) void emd_hungarian_wave(
    const float* __restrict__ p1,
    const float* __restrict__ p2,
    double* __restrict__ batch_mean)
{
    const int b    = blockIdx.x;
    const int lane = threadIdx.x;

    __shared__ float4 s_p1[NPTS];       // p1 points (immutable after setup)
    __shared__ float4 s_q [NPTS];       // p2 points (immutable after setup)
    __shared__ float  s_u [NPTS + 1];   // row potentials (f32)
    __shared__ int    s_p [NPTS + 1];   // p[j] = row matched to column j
    __shared__ int    s_way[NPTS + 1];  // back pointers

    const float* p1b = p1 + (size_t)b * NPTS * 3;
    const float* p2b = p2 + (size_t)b * NPTS * 3;

    float qx[4], qy[4], qz[4];
    #pragma unroll
    for (int k = 0; k < 4; ++k) {
        const int idx = lane + 64 * k;
        s_p1[idx] = make_float4(p1b[idx*3+0], p1b[idx*3+1], p1b[idx*3+2], 0.0f);
        const float a = p2b[idx*3+0], c = p2b[idx*3+1], d = p2b[idx*3+2];
        s_q[idx] = make_float4(a, c, d, 0.0f);
        qx[k] = a; qy[k] = c; qz[k] = d;
        s_p[idx + 1] = 0;
    }
    if (lane == 0) { s_u[0] = 0.0f; s_p[0] = 0; }
    __syncthreads();

    // ---- Phase A: row reduction u[r] = min_j c(r,j) (lane owns 4 rows) ----
    {
        const float4 r0 = s_p1[lane], r1 = s_p1[lane+64],
                     r2 = s_p1[lane+128], r3 = s_p1[lane+192];
        float m0 = FINF, m1 = FINF, m2 = FINF, m3 = FINF;   // min squared dist
        for (int j = 0; j < NPTS; ++j) {
            const float4 q = s_q[j];
            #define D2(R) ((R.x-q.x)*(R.x-q.x) + (R.y-q.y)*(R.y-q.y) + (R.z-q.z)*(R.z-q.z))
            m0 = fminf(m0, D2(r0)); m1 = fminf(m1, D2(r1));
            m2 = fminf(m2, D2(r2)); m3 = fminf(m3, D2(r3));
            #undef D2
        }
        // sqrt is monotone: min_j sqrtf(d2) == sqrtf(min_j d2) exactly
        s_u[lane +   1] = sqrtf(m0);
        s_u[lane +  65] = sqrtf(m1);
        s_u[lane + 129] = sqrtf(m2);
        s_u[lane + 193] = sqrtf(m3);
    }
    __syncthreads();

    // ---- Phase B: column reduction v[j] = min_i (c(i,j) - u[i]) ----
    float v0_ = FINF, v1_ = FINF, v2_ = FINF, v3_ = FINF;
    for (int i2 = 0; i2 < NPTS; ++i2) {
        const float4 rr = s_p1[i2];
        const float  ui = s_u[i2 + 1];
        #define CAND(K, VK)                                                    \
            { const float dx = rr.x - qx[K], dy = rr.y - qy[K], dz = rr.z - qz[K]; \
              const float cd = sqrtf(dx*dx + dy*dy + dz*dz) - ui;              \
              VK = fminf(VK, cd); }
        CAND(0, v0_) CAND(1, v1_) CAND(2, v2_) CAND(3, v3_)
        #undef CAND
    }

    // ---- Phase C: greedy matching on exact zeros of reduced cost ----
    unsigned long long um0 = ~0ull, um1 = ~0ull, um2 = ~0ull, um3 = ~0ull; // unmatched cols
    unsigned long long rm0 = 0, rm1 = 0, rm2 = 0, rm3 = 0;                 // matched rows
    for (int i = 1; i <= NPTS; ++i) {
        const float4 rr = s_p1[i - 1];
        const float  ui = s_u[i];
        bool ok0, ok1, ok2, ok3;
        #define ZCHK(K, VK, UMK, OK)                                           \
            { const float dx = rr.x - qx[K], dy = rr.y - qy[K], dz = rr.z - qz[K]; \
              const float red = (sqrtf(dx*dx + dy*dy + dz*dz) - ui) - VK;      \
              OK = ((UMK >> lane) & 1ull) && (red == 0.0f); }
        ZCHK(0, v0_, um0, ok0) ZCHK(1, v1_, um1, ok1)
        ZCHK(2, v2_, um2, ok2) ZCHK(3, v3_, um3, ok3)
        #undef ZCHK
        const int z = i - 1;
        unsigned long long mA;
        mA = __ballot(ok0);
        if (mA) { const int l = __builtin_ctzll(mA); if (lane == l) s_p[l +   1] = i;
                  um0 &= ~(1ull << l); goto matched; }
        mA = __ballot(ok1);
        if (mA) { const int l = __builtin_ctzll(mA); if (lane == l) s_p[l +  65] = i;
                  um1 &= ~(1ull << l); goto matched; }
        mA = __ballot(ok2);
        if (mA) { const int l = __builtin_ctzll(mA); if (lane == l) s_p[l + 129] = i;
                  um2 &= ~(1ull << l); goto matched; }
        mA = __ballot(ok3);
        if (mA) { const int l = __builtin_ctzll(mA); if (lane == l) s_p[l + 193] = i;
                  um3 &= ~(1ull << l); goto matched; }
        continue;
    matched:
        if      (z <  64) rm0 |= 1ull << z;
        else if (z < 128) rm1 |= 1ull << (z - 64);
        else if (z < 192) rm2 |= 1ull << (z - 128);
        else              rm3 |= 1ull << (z - 192);
    }
    __syncthreads();

    // ---- Main: shortest augmenting path for each unmatched row ----
    for (int i = 1; i <= NPTS; ++i) {
        { const int z = i - 1;
          const unsigned long long r =
              (z < 64) ? rm0 : (z < 128) ? rm1 : (z < 192) ? rm2 : rm3;
          if ((r >> (z & 63)) & 1ull) continue; }

        float M0 = FINF, M1 = FINF, M2 = FINF, M3 = FINF;      // absolute minv
        int   wy0 = 0,   wy1 = 0,   wy2 = 0,   wy3 = 0;        // way
        unsigned usm = 0u;                                     // settled bits K=0..3

        // per-path slot constants: (matched?4:0) | K  (um frozen during path)
        const unsigned mb0 = 0u | ((~(unsigned)(um0 >> lane) & 1u) << 2);
        const unsigned mb1 = 1u | ((~(unsigned)(um1 >> lane) & 1u) << 2);
        const unsigned mb2 = 2u | ((~(unsigned)(um2 >> lane) & 1u) << 2);
        const unsigned mb3 = 3u | ((~(unsigned)(um3 >> lane) & 1u) << 2);

        // path-start prefetch (p/u fixed until path end); u packed in pc.w
        const int   pj0 = s_p[lane + 1];
        const int   pj1 = s_p[lane + 65];
        const int   pj2 = s_p[lane + 129];
        const int   pj3 = s_p[lane + 193];
        float4 pc0 = s_p1[(pj0 > 0 ? pj0 : 1) - 1]; pc0.w = s_u[pj0];
        float4 pc1 = s_p1[(pj1 > 0 ? pj1 : 1) - 1]; pc1.w = s_u[pj1];
        float4 pc2 = s_p1[(pj2 > 0 ? pj2 : 1) - 1]; pc2.w = s_u[pj2];
        float4 pc3 = s_p1[(pj3 > 0 ? pj3 : 1) - 1]; pc3.w = s_u[pj3];
        if (lane == 0) s_p[0] = i;

        const float4 ri = s_p1[i - 1];
        float rx = ri.x, ry = ri.y, rz = ri.z;
        float D  = 0.0f;                // current min (absolute)
        float h  = 0.0f - s_u[i];       // h = D - u[i0]
        int   j0 = 0;
        int   jfin;

        // one settle + advance; `break` exits the enclosing for(;;)
        #define SETTLE_STEP()                                                  \
        {                                                                      \
            /* branchless settle-flag update for previous winner j0 */         \
            const unsigned jp  = (unsigned)(j0 - 1);                           \
            const bool     hit = (j0 != 0) && ((int)(jp & 63u) == lane);       \
            const unsigned bitp = 1u << ((jp >> 6) & 31u);                     \
            if (hit) usm |= bitp;                                              \
            const bool f0 = !(usm & 1u), f1 = !(usm & 2u);                     \
            const bool f2 = !(usm & 4u), f3 = !(usm & 8u);                     \
            /* relax own free columns: cur = c + (h - v_j), clamped >= 0 */    \
            const float w0 = h - v0_, w1 = h - v1_, w2 = h - v2_, w3 = h - v3_;\
            if (f0) { const float dx = rx-qx[0], dy = ry-qy[0], dz = rz-qz[0]; \
                      const float cur = fmaxf(sqrtf(dx*dx+dy*dy+dz*dz) + w0, 0.0f); \
                      if (cur < M0) { M0 = cur; wy0 = j0; } }                  \
            if (f1) { const float dx = rx-qx[1], dy = ry-qy[1], dz = rz-qz[1]; \
                      const float cur = fmaxf(sqrtf(dx*dx+dy*dy+dz*dz) + w1, 0.0f); \
                      if (cur < M1) { M1 = cur; wy1 = j0; } }                  \
            if (f2) { const float dx = rx-qx[2], dy = ry-qy[2], dz = rz-qz[2]; \
                      const float cur = fmaxf(sqrtf(dx*dx+dy*dy+dz*dz) + w2, 0.0f); \
                      if (cur < M2) { M2 = cur; wy2 = j0; } }                  \
            if (f3) { const float dx = rx-qx[3], dy = ry-qy[3], dz = rz-qz[3]; \
                      const float cur = fmaxf(sqrtf(dx*dx+dy*dy+dz*dz) + w3, 0.0f); \
                      if (cur < M3) { M3 = cur; wy3 = j0; } }                  \
            /* packed keys: (bits(M) & ~7) | (matched?4:0) | K */              \
            const unsigned pk0 = f0 ? ((__float_as_uint(M0) & ~7u) | mb0) : 0xFFFFFFFFu; \
            const unsigned pk1 = f1 ? ((__float_as_uint(M1) & ~7u) | mb1) : 0xFFFFFFFFu; \
            const unsigned pk2 = f2 ? ((__float_as_uint(M2) & ~7u) | mb2) : 0xFFFFFFFFu; \
            const unsigned pk3 = f3 ? ((__float_as_uint(M3) & ~7u) | mb3) : 0xFFFFFFFFu; \
            const unsigned pa = (pk0 < pk1) ? pk0 : pk1;                       \
            const unsigned pb = (pk2 < pk3) ? pk2 : pk3;                       \
            const unsigned pl = (pa < pb) ? pa : pb;                           \
            /* 64-lane u32-min reduce (carries flag+K for free) */             \
            unsigned pv = pl;                                                  \
            pv = dpp_umin_step<0x128, 0xF>(pv);   /* row_ror:8  */             \
            pv = dpp_umin_step<0x124, 0xF>(pv);   /* row_ror:4  */             \
            pv = dpp_umin_step<0x39,  0xF>(pv);   /* quad_perm [1,2,3,0] */    \
            pv = dpp_umin_step<0x4E,  0xF>(pv);   /* quad_perm [2,3,0,1] */    \
            pv = dpp_umin_step<0x142, 0xA>(pv);   /* row_bcast:15 */           \
            pv = dpp_umin_step<0x143, 0xC>(pv);   /* row_bcast:31 */           \
            const unsigned pw = (unsigned)__builtin_amdgcn_readlane((int)pv, 63); \
            const float delta = __uint_as_float(pw & ~7u);                     \
            D = delta;                                                         \
            /* winner lane via one ballot; j1 from (lane, K) -- pure SALU */   \
            const unsigned long long mW = __ballot(pl == pw);                  \
            const int lW = __builtin_ctzll(mW);                                \
            const int kW = (int)(pw & 3u);                                     \
            const int j1 = lW + 1 + (kW << 6);                                 \
            /* terminate if winner is unmatched: flag bit 2 of the key */      \
            if (!(pw & 4u)) { jfin = j1; break; }                              \
            /* payload: coords + u (pc.w) of j1's matched row */               \
            float4 sc;                                                         \
            if      (kW == 0) sc = pc0;                                        \
            else if (kW == 1) sc = pc1;                                        \
            else if (kW == 2) sc = pc2;                                        \
            else              sc = pc3;                                        \
            rx = readlane_f32(sc.x, lW);                                       \
            ry = readlane_f32(sc.y, lW);                                       \
            rz = readlane_f32(sc.z, lW);                                       \
            h  = D - readlane_f32(sc.w, lW);                                   \
            j0 = j1;                                                           \
        }

        for (;;) {
            SETTLE_STEP();
            SETTLE_STEP();
        }
        #undef SETTLE_STEP

        // path end: dump ways, apply deferred potential updates
        s_way[lane + 1]   = wy0;
        s_way[lane + 65]  = wy1;
        s_way[lane + 129] = wy2;
        s_way[lane + 193] = wy3;
        if (usm & 1u) { const float adj = D - M0; v0_ -= adj; s_u[pj0] += adj; }
        if (usm & 2u) { const float adj = D - M1; v1_ -= adj; s_u[pj1] += adj; }
        if (usm & 4u) { const float adj = D - M2; v2_ -= adj; s_u[pj2] += adj; }
        if (usm & 8u) { const float adj = D - M3; v3_ -= adj; s_u[pj3] += adj; }
        if (lane == 0) s_u[i] += D;   // path root (settle-D = 0)
        __syncthreads();

        if (lane == 0) {               // augment alternating path (serial)
            int j = jfin;
            while (j != 0) { const int jp = s_way[j]; s_p[j] = s_p[jp]; j = jp; }
        }
        { const int jz = jfin - 1;
          const unsigned long long m = ~(1ull << (jz & 63));
          const int k4 = jz >> 6;
          if      (k4 == 0) um0 &= m;
          else if (k4 == 1) um1 &= m;
          else if (k4 == 2) um2 &= m;
          else              um3 &= m; }
        __syncthreads();
    }

    // mean matched cost for this batch (f64 sum of f32 costs, as reference)
    double s = 0.0;
    #pragma unroll
    for (int k = 0; k < 4; ++k) {
        const int idx = lane + 64 * k;
        const int r   = s_p[idx + 1] - 1;
        const float4 rr = s_p1[r];
        const float dx = rr.x - qx[k];
        const float dy = rr.y - qy[k];
        const float dz = rr.z - qz[k];
        s += (double)sqrtf(dx*dx + dy*dy + dz*dz);
    }
    #pragma unroll
    for (int off = 1; off < 64; off <<= 1) s += __shfl_xor(s, off, 64);
    if (lane == 0) batch_mean[b] = s / (double)NPTS;
}

__global__ void emd_finalize_kernel(const double* __restrict__ bm,
                                    float* __restrict__ out)
{
    double s = 0.0;
    #pragma unroll
    for (int i = 0; i < NBATCH; ++i) s += bm[i];
    out[0] = (float)(s / (double)NBATCH);
}

extern "C" void kernel_launch(void* const* d_in, const int* in_sizes, int n_in,
                              void* d_out, int out_size, void* d_ws, size_t ws_size,
                              hipStream_t stream)
{
    const float* p1 = (const float*)d_in[0];   // [B, N, 3] f32
    const float* p2 = (const float*)d_in[1];   // [B, N, 3] f32
    double* bm = (double*)d_ws;                // 32 doubles of scratch

    emd_hungarian_wave<<<NBATCH, 64, 0, stream>>>(p1, p2, bm);
    emd_finalize_kernel<<<1, 1, 0, stream>>>(bm, (float*)d_out);
}